// Round 6
// baseline (1389.848 us; speedup 1.0000x reference)
//
#include <hip/hip_runtime.h>
#include <hip/hip_bf16.h>

#define IN_F 108   // concat(x[107], votes[1])
#define XD   107
#define HID  128
#define OUTD 64
#define H1S  132   // padded LDS stride for 128-wide rows
#define CHUNK 1024 // scan chunk per block
#define SEG_NODES 512

typedef unsigned short ushort_t;
typedef unsigned int uint_t;

__device__ inline void atomicMaxF(float* addr, float val) {
    if (val >= 0.f) atomicMax((int*)addr, __float_as_int(val));
    else            atomicMin((unsigned int*)addr, __float_as_uint(val));
}

__device__ inline ushort_t f2bf(float f) {
    uint_t b = __float_as_uint(f);
    return (ushort_t)((b + 0x7fffu + ((b >> 16) & 1u)) >> 16);   // RNE
}

__device__ inline float bf2f(ushort_t u) {
    return __uint_as_float((uint_t)u << 16);
}

__device__ inline float4 fma4(float a, const float4 b, float4 c) {
    c.x += a * b.x; c.y += a * b.y; c.z += a * b.z; c.w += a * b.w; return c;
}

__global__ void init_out_kernel(float* out, int n) {
    int i = blockIdx.x * 256 + threadIdx.x;
    if (i < n) out[i] = -__builtin_inff();
}

// ---- CSR build ----------------------------------------------------------
__global__ void hist_kernel(const int* __restrict__ dst, int* __restrict__ deg_i, int E) {
    int e = blockIdx.x * 256 + threadIdx.x;
    if (e < E) atomicAdd(&deg_i[dst[e]], 1);
}

__global__ __launch_bounds__(256) void chunk_sum_kernel(const int* __restrict__ deg_i,
                                                        int* __restrict__ bsum, int N) {
    int base = blockIdx.x * CHUNK;
    int v = 0;
    for (int i = threadIdx.x; i < CHUNK; i += 256) {
        int idx = base + i;
        if (idx < N) v += deg_i[idx];
    }
#pragma unroll
    for (int d = 1; d < 64; d <<= 1) v += __shfl_xor(v, d);
    __shared__ int red[4];
    int wid = threadIdx.x >> 6;
    if ((threadIdx.x & 63) == 0) red[wid] = v;
    __syncthreads();
    if (threadIdx.x == 0) bsum[blockIdx.x] = red[0] + red[1] + red[2] + red[3];
}

__global__ __launch_bounds__(64) void scan_bsum_kernel(const int* __restrict__ bsum,
                                                       int* __restrict__ bsum_ex, int nb) {
    int lane = threadIdx.x;
    int carry = 0;
    for (int b = 0; b < nb; b += 64) {
        int i = b + lane;
        int orig = (i < nb) ? bsum[i] : 0;
        int v = orig;
#pragma unroll
        for (int d = 1; d < 64; d <<= 1) {
            int t = __shfl_up(v, d);
            if (lane >= d) v += t;
        }
        if (i < nb) bsum_ex[i] = carry + v - orig;
        carry += __shfl(v, 63);
    }
}

__global__ __launch_bounds__(256) void write_rows_kernel(const int* __restrict__ deg_i,
                                                         const int* __restrict__ bsum_ex,
                                                         int* __restrict__ row_start,
                                                         int* __restrict__ cursor,
                                                         int N, int E) {
    __shared__ int s[256];
    int base = blockIdx.x * CHUNK;
    int i0 = base + threadIdx.x * 4;
    int d0 = 0, d1 = 0, d2 = 0, d3 = 0;
    if (i0 + 3 < N) {
        int4 q = *(const int4*)(deg_i + i0);
        d0 = q.x; d1 = q.y; d2 = q.z; d3 = q.w;
    } else {
        if (i0 + 0 < N) d0 = deg_i[i0 + 0];
        if (i0 + 1 < N) d1 = deg_i[i0 + 1];
        if (i0 + 2 < N) d2 = deg_i[i0 + 2];
        if (i0 + 3 < N) d3 = deg_i[i0 + 3];
    }
    int tsum = d0 + d1 + d2 + d3;
    s[threadIdx.x] = tsum;
    __syncthreads();
    for (int d = 1; d < 256; d <<= 1) {
        int t = (threadIdx.x >= d) ? s[threadIdx.x - d] : 0;
        __syncthreads();
        s[threadIdx.x] += t;
        __syncthreads();
    }
    int off = bsum_ex[blockIdx.x] + s[threadIdx.x] - tsum;
    if (i0 + 0 < N) { row_start[i0 + 0] = off; cursor[i0 + 0] = off; off += d0; }
    if (i0 + 1 < N) { row_start[i0 + 1] = off; cursor[i0 + 1] = off; off += d1; }
    if (i0 + 2 < N) { row_start[i0 + 2] = off; cursor[i0 + 2] = off; off += d2; }
    if (i0 + 3 < N) { row_start[i0 + 3] = off; cursor[i0 + 3] = off; off += d3; }
    if (blockIdx.x == 0 && threadIdx.x == 0) row_start[N] = E;
}

__global__ void place_kernel(const int* __restrict__ src, const int* __restrict__ dst,
                             int* __restrict__ cursor, int* __restrict__ sorted_src, int E) {
    int e = blockIdx.x * 256 + threadIdx.x;
    if (e >= E) return;
    int pos = atomicAdd(&cursor[dst[e]], 1);
    sorted_src[pos] = src[e];
}

// ---- bf16 copy of h0 ----------------------------------------------------
__global__ void convert_kernel(const float* __restrict__ x, const float* __restrict__ votes,
                               ushort_t* __restrict__ xb, int N) {
    int idx = blockIdx.x * 256 + threadIdx.x;
    if (idx >= N * IN_F) return;
    int n = idx / IN_F, f = idx - n * IN_F;
    float v = (f < XD) ? x[n * XD + f] : votes[n];
    xb[idx] = f2bf(v);
}

// ---- gather-mean layer 1 (bf16 in, f32 accum, bf16 out, pre-divided) ----
__global__ __launch_bounds__(256) void gather1_kernel(
        const ushort_t* __restrict__ xb,
        const int* __restrict__ row_start, const int* __restrict__ sorted_src,
        ushort_t* __restrict__ agg1b, int N) {
    int node = (blockIdx.x * 256 + threadIdx.x) >> 6;
    int lane = threadIdx.x & 63;
    if (node >= N) return;
    int rs = row_start[node], re = row_start[node + 1];
    int h  = lane >> 5;
    int l2 = lane & 31;
    float a0 = 0.f, a1 = 0.f, a2 = 0.f, a3 = 0.f;
    for (int k0 = rs; k0 < re; k0 += 64) {
        int cnt = min(64, re - k0);
        int sl = sorted_src[k0 + min(lane, cnt - 1)];
        for (int t = 0; t < cnt; t += 2) {
            int tt = min(t + h, cnt - 1);
            int s = __shfl(sl, tt);
            if (t + h < cnt && l2 < 27) {
                uint2 w = *(const uint2*)(xb + s * IN_F + 4 * l2);
                a0 += __uint_as_float(w.x << 16);
                a1 += __uint_as_float(w.x & 0xffff0000u);
                a2 += __uint_as_float(w.y << 16);
                a3 += __uint_as_float(w.y & 0xffff0000u);
            }
        }
    }
    a0 += __shfl_xor(a0, 32);
    a1 += __shfl_xor(a1, 32);
    a2 += __shfl_xor(a2, 32);
    a3 += __shfl_xor(a3, 32);
    float inv = 1.f / fmaxf((float)(re - rs), 1.f);
    if (lane < 27) {
        ushort4 p;
        p.x = f2bf(a0 * inv);
        p.y = f2bf(a1 * inv);
        p.z = f2bf(a2 * inv);
        p.w = f2bf(a3 * inv);
        *(ushort4*)(agg1b + node * IN_F + 4 * lane) = p;
    }
}

// ---- gather-mean of u (bf16, 64 dims) -----------------------------------
__global__ __launch_bounds__(256) void gatheru_kernel(
        const ushort_t* __restrict__ ub,
        const int* __restrict__ row_start, const int* __restrict__ sorted_src,
        float* __restrict__ aggu, int N) {
    int node = (blockIdx.x * 256 + threadIdx.x) >> 6;
    int lane = threadIdx.x & 63;
    if (node >= N) return;
    int rs = row_start[node], re = row_start[node + 1];
    int g  = lane >> 4;
    int l4 = lane & 15;
    float a0 = 0.f, a1 = 0.f, a2 = 0.f, a3 = 0.f;
    for (int k0 = rs; k0 < re; k0 += 64) {
        int cnt = min(64, re - k0);
        int sl = sorted_src[k0 + min(lane, cnt - 1)];
        for (int t = 0; t < cnt; t += 4) {
            int tt = min(t + g, cnt - 1);
            int s = __shfl(sl, tt);
            if (t + g < cnt) {
                uint2 w = *(const uint2*)(ub + (s << 6) + 4 * l4);
                a0 += __uint_as_float(w.x << 16);
                a1 += __uint_as_float(w.x & 0xffff0000u);
                a2 += __uint_as_float(w.y << 16);
                a3 += __uint_as_float(w.y & 0xffff0000u);
            }
        }
    }
    a0 += __shfl_xor(a0, 16); a0 += __shfl_xor(a0, 32);
    a1 += __shfl_xor(a1, 16); a1 += __shfl_xor(a1, 32);
    a2 += __shfl_xor(a2, 16); a2 += __shfl_xor(a2, 32);
    a3 += __shfl_xor(a3, 16); a3 += __shfl_xor(a3, 32);
    float inv = 1.f / fmaxf((float)(re - rs), 1.f);
    if (lane < 16) {
        *(float4*)(aggu + (node << 6) + 4 * lane) =
            make_float4(a0 * inv, a1 * inv, a2 * inv, a3 * inv);
    }
}

// ---- pipelined weight-load helpers --------------------------------------
__device__ inline void load_w2(const float* __restrict__ wl, const float* __restrict__ wr,
                               int k, float4 wlv[4], float4 wrv[4]) {
#pragma unroll
    for (int kk = 0; kk < 4; ++kk) {
        wlv[kk] = *(const float4*)(wl + (k + kk) * HID);
        wrv[kk] = *(const float4*)(wr + (k + kk) * HID);
    }
}

__device__ inline void fma_g1(const float* __restrict__ sh_ag, const float* __restrict__ sh_h0,
                              int mq, int k, const float4 wlv[4], const float4 wrv[4],
                              float4 acc[4]) {
#pragma unroll
    for (int mm = 0; mm < 4; ++mm) {
        const int row = (mq * 4 + mm) * IN_F + k;
        float4 ag = *(const float4*)(sh_ag + row);
        float4 h0 = *(const float4*)(sh_h0 + row);
        acc[mm] = fma4(ag.x, wlv[0], acc[mm]);
        acc[mm] = fma4(ag.y, wlv[1], acc[mm]);
        acc[mm] = fma4(ag.z, wlv[2], acc[mm]);
        acc[mm] = fma4(ag.w, wlv[3], acc[mm]);
        acc[mm] = fma4(h0.x, wrv[0], acc[mm]);
        acc[mm] = fma4(h0.y, wrv[1], acc[mm]);
        acc[mm] = fma4(h0.z, wrv[2], acc[mm]);
        acc[mm] = fma4(h0.w, wrv[3], acc[mm]);
    }
}

__device__ inline void load_w1(const float* __restrict__ w, int k, float4 wv[4]) {
#pragma unroll
    for (int kk = 0; kk < 4; ++kk)
        wv[kk] = *(const float4*)(w + (k + kk) * OUTD);
}

__device__ inline void fma_g2(const float* __restrict__ sh, int mq2, int k,
                              const float4 wv[4], float4 acc[4]) {
#pragma unroll
    for (int mm = 0; mm < 4; ++mm) {
        float4 hv = *(const float4*)(sh + (mq2 * 4 + mm) * H1S + k);
        acc[mm] = fma4(hv.x, wv[0], acc[mm]);
        acc[mm] = fma4(hv.y, wv[1], acc[mm]);
        acc[mm] = fma4(hv.z, wv[2], acc[mm]);
        acc[mm] = fma4(hv.w, wv[3], acc[mm]);
    }
}

// ---- layer-1 dense + fused u=h1@W2l (bf16) and v=h1@W2r (f32) -----------
// h1 lives only in LDS — never written to global.
#define T1_M 32
__global__ __launch_bounds__(256, 4) void gemm1_kernel(
        const float* __restrict__ x, const float* __restrict__ votes,
        const ushort_t* __restrict__ agg1b,
        const float* __restrict__ W1l, const float* __restrict__ b1,
        const float* __restrict__ W1r, const float* __restrict__ W2l,
        const float* __restrict__ W2r,
        ushort_t* __restrict__ ub, float* __restrict__ vv, int N) {
    __shared__ float smem[2 * T1_M * IN_F];          // 27.6 KB; phase2 reuses [32][H1S]
    float* sh_ag = smem;
    float* sh_h0 = smem + T1_M * IN_F;
    int n0 = blockIdx.x * T1_M;
    for (int i = threadIdx.x; i < T1_M * IN_F; i += 256) {
        int m = i / IN_F, k = i - m * IN_F;
        int n = n0 + m;
        float h0v = 0.f, agv = 0.f;
        if (n < N) {
            h0v = (k < XD) ? x[n * XD + k] : votes[n];
            agv = bf2f(agg1b[n * IN_F + k]);
        }
        sh_h0[i] = h0v;
        sh_ag[i] = agv;
    }
    __syncthreads();

    int jq = threadIdx.x & 31;          // j0 = jq*4
    int mq = threadIdx.x >> 5;          // nodes mq*4+mm
    float4 acc[4] = {};
    const float* wl = W1l + jq * 4;
    const float* wr = W1r + jq * 4;
    // software-pipelined: A/B weight buffers, groups of 4 k, IN_F=108 -> 27 groups
    float4 wlA[4], wrA[4], wlB[4], wrB[4];
    load_w2(wl, wr, 0, wlA, wrA);
#pragma unroll
    for (int k = 0; k <= 96; k += 8) {
        load_w2(wl, wr, k + 4, wlB, wrB);
        fma_g1(sh_ag, sh_h0, mq, k, wlA, wrA, acc);
        if (k + 8 <= 104) load_w2(wl, wr, k + 8, wlA, wrA);
        fma_g1(sh_ag, sh_h0, mq, k + 4, wlB, wrB, acc);
    }
    fma_g1(sh_ag, sh_h0, mq, 104, wlA, wrA, acc);

    float4 bv = *(const float4*)(b1 + jq * 4);
    float4 rr[4];
#pragma unroll
    for (int mm = 0; mm < 4; ++mm) {
        rr[mm].x = fmaxf(acc[mm].x + bv.x, 0.f);
        rr[mm].y = fmaxf(acc[mm].y + bv.y, 0.f);
        rr[mm].z = fmaxf(acc[mm].z + bv.z, 0.f);
        rr[mm].w = fmaxf(acc[mm].w + bv.w, 0.f);
    }

    // phase 2: [u|v] = relu(h1_tile) @ [W2l|W2r]
    __syncthreads();
#pragma unroll
    for (int mm = 0; mm < 4; ++mm)
        *(float4*)(smem + (mq * 4 + mm) * H1S + jq * 4) = rr[mm];
    __syncthreads();

    int jq2 = threadIdx.x & 31;         // j4 over combined 128 outputs
    int mq2 = threadIdx.x >> 5;         // nodes mq2*4+mm
    float4 acc2[4] = {};
    const float* w2 = ((jq2 < 16) ? W2l + jq2 * 4 : W2r + (jq2 - 16) * 4);
    float4 wA[4], wB[4];
    load_w1(w2, 0, wA);
#pragma unroll
    for (int k = 0; k <= 112; k += 8) {
        load_w1(w2, k + 4, wB);
        fma_g2(smem, mq2, k, wA, acc2);
        if (k + 8 <= 120) load_w1(w2, k + 8, wA);
        fma_g2(smem, mq2, k + 4, wB, acc2);
    }
    load_w1(w2, 124, wB);
    fma_g2(smem, mq2, 120, wA, acc2);
    fma_g2(smem, mq2, 124, wB, acc2);

#pragma unroll
    for (int mm = 0; mm < 4; ++mm) {
        int n = n0 + mq2 * 4 + mm;
        if (n < N) {
            if (jq2 < 16) {
                ushort4 p;
                p.x = f2bf(acc2[mm].x);
                p.y = f2bf(acc2[mm].y);
                p.z = f2bf(acc2[mm].z);
                p.w = f2bf(acc2[mm].w);
                *(ushort4*)(ub + (n << 6) + jq2 * 4) = p;
            } else {
                *(float4*)(vv + (n << 6) + (jq2 - 16) * 4) = acc2[mm];
            }
        }
    }
}

// ---- finalize: h2 = aggu + v + b2, then run-length segment-max ----------
__global__ __launch_bounds__(256) void finalize_kernel(
        const float* __restrict__ aggu, const float* __restrict__ vv,
        const float* __restrict__ b2, const int* __restrict__ batch,
        float* __restrict__ out, int N) {
    int j  = threadIdx.x & 63;
    int nq = threadIdx.x >> 6;
    int n0 = blockIdx.x * SEG_NODES;
    float bj = b2[j];
    int curg = -1;
    float curm = -__builtin_inff();
    for (int m = nq; m < SEG_NODES; m += 4) {
        int n = n0 + m;
        if (n >= N) break;
        int g = batch[n];
        float v = aggu[(n << 6) + j] + vv[(n << 6) + j] + bj;
        if (g != curg) {
            if (curg >= 0) atomicMaxF(&out[(curg << 6) + j], curm);
            curg = g;
            curm = v;
        } else {
            curm = fmaxf(curm, v);
        }
    }
    if (curg >= 0) atomicMaxF(&out[(curg << 6) + j], curm);
}

static inline size_t align256(size_t v) { return (v + 255) & ~(size_t)255; }

extern "C" void kernel_launch(void* const* d_in, const int* in_sizes, int n_in,
                              void* d_out, int out_size, void* d_ws, size_t ws_size,
                              hipStream_t stream) {
    const float* x     = (const float*)d_in[0];
    const float* votes = (const float*)d_in[1];
    const int*   eidx  = (const int*)d_in[2];
    const int*   batch = (const int*)d_in[3];
    const float* W1l   = (const float*)d_in[4];
    const float* b1    = (const float*)d_in[5];
    const float* W1r   = (const float*)d_in[6];
    const float* W2l   = (const float*)d_in[7];
    const float* b2    = (const float*)d_in[8];
    const float* W2r   = (const float*)d_in[9];
    float* out = (float*)d_out;

    const int N = in_sizes[1];
    const int E = in_sizes[2] / 2;
    const int* src = eidx;
    const int* dst = eidx + E;
    const int nb = (N + CHUNK - 1) / CHUNK;

    char* ws = (char*)d_ws;
    size_t off = 0;
    int* deg_i      = (int*)(ws + off); off = align256(off + (size_t)N * 4);
    int* row_start  = (int*)(ws + off); off = align256(off + (size_t)(N + 1) * 4);
    int* cursor     = (int*)(ws + off); off = align256(off + (size_t)N * 4);
    int* bsum       = (int*)(ws + off); off = align256(off + (size_t)nb * 4);
    int* bsum_ex    = (int*)(ws + off); off = align256(off + (size_t)nb * 4);
    int* sorted_src = (int*)(ws + off); off = align256(off + (size_t)E * 4);
    ushort_t* xb    = (ushort_t*)(ws + off); off = align256(off + (size_t)N * IN_F * 2);
    ushort_t* agg1b = (ushort_t*)(ws + off); off = align256(off + (size_t)N * IN_F * 2);
    ushort_t* ub    = (ushort_t*)(ws + off); off = align256(off + (size_t)N * OUTD * 2);
    float* vv       = (float*)(ws + off); off = align256(off + (size_t)N * OUTD * 4);
    float* aggu     = (float*)(ws + off); off = align256(off + (size_t)N * OUTD * 4);

    hipMemsetAsync(deg_i, 0, (size_t)N * 4, stream);
    init_out_kernel<<<(out_size + 255) / 256, 256, 0, stream>>>(out, out_size);

    // CSR
    hist_kernel<<<(E + 255) / 256, 256, 0, stream>>>(dst, deg_i, E);
    chunk_sum_kernel<<<nb, 256, 0, stream>>>(deg_i, bsum, N);
    scan_bsum_kernel<<<1, 64, 0, stream>>>(bsum, bsum_ex, nb);
    write_rows_kernel<<<nb, 256, 0, stream>>>(deg_i, bsum_ex, row_start, cursor, N, E);
    place_kernel<<<(E + 255) / 256, 256, 0, stream>>>(src, dst, cursor, sorted_src, E);

    // h0 -> bf16
    convert_kernel<<<(N * IN_F + 255) / 256, 256, 0, stream>>>(x, votes, xb, N);

    // layer 1 aggregate + both dense layers' matmuls (h1 stays in LDS)
    gather1_kernel<<<(N + 3) / 4, 256, 0, stream>>>(xb, row_start, sorted_src, agg1b, N);
    gemm1_kernel<<<(N + T1_M - 1) / T1_M, 256, 0, stream>>>(x, votes, agg1b, W1l, b1, W1r,
                                                            W2l, W2r, ub, vv, N);
    // layer 2 aggregate (64 dims, bf16)
    gatheru_kernel<<<(N + 3) / 4, 256, 0, stream>>>(ub, row_start, sorted_src, aggu, N);

    // h2 = aggu + v + b2, fused with segment-max
    finalize_kernel<<<(N + SEG_NODES - 1) / SEG_NODES, 256, 0, stream>>>(
        aggu, vv, b2, batch, out, N);
}

// Round 7
// 303.589 us; speedup vs baseline: 4.5781x; 4.5781x over previous
//
#include <hip/hip_runtime.h>
#include <hip/hip_bf16.h>

#define IN_F 108   // concat(x[107], votes[1])
#define XD   107
#define HID  128
#define OUTD 64
#define H1S  132   // padded LDS stride for 128-wide rows
#define CHUNK 1024 // scan chunk per block
#define SEG_NODES 512

typedef unsigned short ushort_t;
typedef unsigned int uint_t;

__device__ inline void atomicMaxF(float* addr, float val) {
    if (val >= 0.f) atomicMax((int*)addr, __float_as_int(val));
    else            atomicMin((unsigned int*)addr, __float_as_uint(val));
}

__device__ inline ushort_t f2bf(float f) {
    uint_t b = __float_as_uint(f);
    return (ushort_t)((b + 0x7fffu + ((b >> 16) & 1u)) >> 16);   // RNE
}

__device__ inline float bf2f(ushort_t u) {
    return __uint_as_float((uint_t)u << 16);
}

__device__ inline float4 fma4(float a, const float4 b, float4 c) {
    c.x += a * b.x; c.y += a * b.y; c.z += a * b.z; c.w += a * b.w; return c;
}

__global__ void init_out_kernel(float* out, int n) {
    int i = blockIdx.x * 256 + threadIdx.x;
    if (i < n) out[i] = -__builtin_inff();
}

// ---- CSR build ----------------------------------------------------------
__global__ void hist_kernel(const int* __restrict__ dst, int* __restrict__ deg_i, int E) {
    int e = blockIdx.x * 256 + threadIdx.x;
    if (e < E) atomicAdd(&deg_i[dst[e]], 1);
}

__global__ __launch_bounds__(256) void chunk_sum_kernel(const int* __restrict__ deg_i,
                                                        int* __restrict__ bsum, int N) {
    int base = blockIdx.x * CHUNK;
    int v = 0;
    for (int i = threadIdx.x; i < CHUNK; i += 256) {
        int idx = base + i;
        if (idx < N) v += deg_i[idx];
    }
#pragma unroll
    for (int d = 1; d < 64; d <<= 1) v += __shfl_xor(v, d);
    __shared__ int red[4];
    int wid = threadIdx.x >> 6;
    if ((threadIdx.x & 63) == 0) red[wid] = v;
    __syncthreads();
    if (threadIdx.x == 0) bsum[blockIdx.x] = red[0] + red[1] + red[2] + red[3];
}

__global__ __launch_bounds__(64) void scan_bsum_kernel(const int* __restrict__ bsum,
                                                       int* __restrict__ bsum_ex, int nb) {
    int lane = threadIdx.x;
    int carry = 0;
    for (int b = 0; b < nb; b += 64) {
        int i = b + lane;
        int orig = (i < nb) ? bsum[i] : 0;
        int v = orig;
#pragma unroll
        for (int d = 1; d < 64; d <<= 1) {
            int t = __shfl_up(v, d);
            if (lane >= d) v += t;
        }
        if (i < nb) bsum_ex[i] = carry + v - orig;
        carry += __shfl(v, 63);
    }
}

__global__ __launch_bounds__(256) void write_rows_kernel(const int* __restrict__ deg_i,
                                                         const int* __restrict__ bsum_ex,
                                                         int* __restrict__ row_start,
                                                         int* __restrict__ cursor,
                                                         int N, int E) {
    __shared__ int s[256];
    int base = blockIdx.x * CHUNK;
    int i0 = base + threadIdx.x * 4;
    int d0 = 0, d1 = 0, d2 = 0, d3 = 0;
    if (i0 + 3 < N) {
        int4 q = *(const int4*)(deg_i + i0);
        d0 = q.x; d1 = q.y; d2 = q.z; d3 = q.w;
    } else {
        if (i0 + 0 < N) d0 = deg_i[i0 + 0];
        if (i0 + 1 < N) d1 = deg_i[i0 + 1];
        if (i0 + 2 < N) d2 = deg_i[i0 + 2];
        if (i0 + 3 < N) d3 = deg_i[i0 + 3];
    }
    int tsum = d0 + d1 + d2 + d3;
    s[threadIdx.x] = tsum;
    __syncthreads();
    for (int d = 1; d < 256; d <<= 1) {
        int t = (threadIdx.x >= d) ? s[threadIdx.x - d] : 0;
        __syncthreads();
        s[threadIdx.x] += t;
        __syncthreads();
    }
    int off = bsum_ex[blockIdx.x] + s[threadIdx.x] - tsum;
    if (i0 + 0 < N) { row_start[i0 + 0] = off; cursor[i0 + 0] = off; off += d0; }
    if (i0 + 1 < N) { row_start[i0 + 1] = off; cursor[i0 + 1] = off; off += d1; }
    if (i0 + 2 < N) { row_start[i0 + 2] = off; cursor[i0 + 2] = off; off += d2; }
    if (i0 + 3 < N) { row_start[i0 + 3] = off; cursor[i0 + 3] = off; off += d3; }
    if (blockIdx.x == 0 && threadIdx.x == 0) row_start[N] = E;
}

__global__ void place_kernel(const int* __restrict__ src, const int* __restrict__ dst,
                             int* __restrict__ cursor, int* __restrict__ sorted_src, int E) {
    int e = blockIdx.x * 256 + threadIdx.x;
    if (e >= E) return;
    int pos = atomicAdd(&cursor[dst[e]], 1);
    sorted_src[pos] = src[e];
}

// ---- bf16 copy of h0 ----------------------------------------------------
__global__ void convert_kernel(const float* __restrict__ x, const float* __restrict__ votes,
                               ushort_t* __restrict__ xb, int N) {
    int idx = blockIdx.x * 256 + threadIdx.x;
    if (idx >= N * IN_F) return;
    int n = idx / IN_F, f = idx - n * IN_F;
    float v = (f < XD) ? x[n * XD + f] : votes[n];
    xb[idx] = f2bf(v);
}

// ---- gather-mean layer 1 (bf16 in, f32 accum, bf16 out, pre-divided) ----
__global__ __launch_bounds__(256) void gather1_kernel(
        const ushort_t* __restrict__ xb,
        const int* __restrict__ row_start, const int* __restrict__ sorted_src,
        ushort_t* __restrict__ agg1b, int N) {
    int node = (blockIdx.x * 256 + threadIdx.x) >> 6;
    int lane = threadIdx.x & 63;
    if (node >= N) return;
    int rs = row_start[node], re = row_start[node + 1];
    int h  = lane >> 5;
    int l2 = lane & 31;
    float a0 = 0.f, a1 = 0.f, a2 = 0.f, a3 = 0.f;
    for (int k0 = rs; k0 < re; k0 += 64) {
        int cnt = min(64, re - k0);
        int sl = sorted_src[k0 + min(lane, cnt - 1)];
        for (int t = 0; t < cnt; t += 2) {
            int tt = min(t + h, cnt - 1);
            int s = __shfl(sl, tt);
            if (t + h < cnt && l2 < 27) {
                uint2 w = *(const uint2*)(xb + s * IN_F + 4 * l2);
                a0 += __uint_as_float(w.x << 16);
                a1 += __uint_as_float(w.x & 0xffff0000u);
                a2 += __uint_as_float(w.y << 16);
                a3 += __uint_as_float(w.y & 0xffff0000u);
            }
        }
    }
    a0 += __shfl_xor(a0, 32);
    a1 += __shfl_xor(a1, 32);
    a2 += __shfl_xor(a2, 32);
    a3 += __shfl_xor(a3, 32);
    float inv = 1.f / fmaxf((float)(re - rs), 1.f);
    if (lane < 27) {
        ushort4 p;
        p.x = f2bf(a0 * inv);
        p.y = f2bf(a1 * inv);
        p.z = f2bf(a2 * inv);
        p.w = f2bf(a3 * inv);
        *(ushort4*)(agg1b + node * IN_F + 4 * lane) = p;
    }
}

// ---- gather-mean of u (bf16, 64 dims) -----------------------------------
__global__ __launch_bounds__(256) void gatheru_kernel(
        const ushort_t* __restrict__ ub,
        const int* __restrict__ row_start, const int* __restrict__ sorted_src,
        float* __restrict__ aggu, int N) {
    int node = (blockIdx.x * 256 + threadIdx.x) >> 6;
    int lane = threadIdx.x & 63;
    if (node >= N) return;
    int rs = row_start[node], re = row_start[node + 1];
    int g  = lane >> 4;
    int l4 = lane & 15;
    float a0 = 0.f, a1 = 0.f, a2 = 0.f, a3 = 0.f;
    for (int k0 = rs; k0 < re; k0 += 64) {
        int cnt = min(64, re - k0);
        int sl = sorted_src[k0 + min(lane, cnt - 1)];
        for (int t = 0; t < cnt; t += 4) {
            int tt = min(t + g, cnt - 1);
            int s = __shfl(sl, tt);
            if (t + g < cnt) {
                uint2 w = *(const uint2*)(ub + (s << 6) + 4 * l4);
                a0 += __uint_as_float(w.x << 16);
                a1 += __uint_as_float(w.x & 0xffff0000u);
                a2 += __uint_as_float(w.y << 16);
                a3 += __uint_as_float(w.y & 0xffff0000u);
            }
        }
    }
    a0 += __shfl_xor(a0, 16); a0 += __shfl_xor(a0, 32);
    a1 += __shfl_xor(a1, 16); a1 += __shfl_xor(a1, 32);
    a2 += __shfl_xor(a2, 16); a2 += __shfl_xor(a2, 32);
    a3 += __shfl_xor(a3, 16); a3 += __shfl_xor(a3, 32);
    float inv = 1.f / fmaxf((float)(re - rs), 1.f);
    if (lane < 16) {
        *(float4*)(aggu + (node << 6) + 4 * lane) =
            make_float4(a0 * inv, a1 * inv, a2 * inv, a3 * inv);
    }
}

// ---- layer-1 dense + fused u=h1@W2l (bf16) and v=h1@W2r (f32) -----------
// h1 lives only in LDS — never written to global.
// R5-proven loop bodies: float4 arrays declared in-loop, compile-time indexed.
#define T1_M 32
__global__ __launch_bounds__(256) void gemm1_kernel(
        const float* __restrict__ x, const float* __restrict__ votes,
        const ushort_t* __restrict__ agg1b,
        const float* __restrict__ W1l, const float* __restrict__ b1,
        const float* __restrict__ W1r, const float* __restrict__ W2l,
        const float* __restrict__ W2r,
        ushort_t* __restrict__ ub, float* __restrict__ vv, int N) {
    __shared__ float smem[2 * T1_M * IN_F];          // 27.6 KB; phase2 reuses [32][H1S]
    float* sh_ag = smem;
    float* sh_h0 = smem + T1_M * IN_F;
    int n0 = blockIdx.x * T1_M;
    for (int i = threadIdx.x; i < T1_M * IN_F; i += 256) {
        int m = i / IN_F, k = i - m * IN_F;
        int n = n0 + m;
        float h0v = 0.f, agv = 0.f;
        if (n < N) {
            h0v = (k < XD) ? x[n * XD + k] : votes[n];
            agv = bf2f(agg1b[n * IN_F + k]);
        }
        sh_h0[i] = h0v;
        sh_ag[i] = agv;
    }
    __syncthreads();

    int jq = threadIdx.x & 31;          // j0 = jq*4
    int mq = threadIdx.x >> 5;          // nodes mq*4+mm
    float4 acc[4] = {};
    const float* wl = W1l + jq * 4;
    const float* wr = W1r + jq * 4;
#pragma unroll 2
    for (int k = 0; k < IN_F; k += 4) {
        float4 wlv[4], wrv[4];
#pragma unroll
        for (int kk = 0; kk < 4; ++kk) {
            wlv[kk] = *(const float4*)(wl + (k + kk) * HID);
            wrv[kk] = *(const float4*)(wr + (k + kk) * HID);
        }
#pragma unroll
        for (int mm = 0; mm < 4; ++mm) {
            const int row = (mq * 4 + mm) * IN_F + k;
            float4 ag = *(const float4*)(sh_ag + row);
            float4 h0 = *(const float4*)(sh_h0 + row);
            acc[mm] = fma4(ag.x, wlv[0], acc[mm]);
            acc[mm] = fma4(ag.y, wlv[1], acc[mm]);
            acc[mm] = fma4(ag.z, wlv[2], acc[mm]);
            acc[mm] = fma4(ag.w, wlv[3], acc[mm]);
            acc[mm] = fma4(h0.x, wrv[0], acc[mm]);
            acc[mm] = fma4(h0.y, wrv[1], acc[mm]);
            acc[mm] = fma4(h0.z, wrv[2], acc[mm]);
            acc[mm] = fma4(h0.w, wrv[3], acc[mm]);
        }
    }
    float4 bv = *(const float4*)(b1 + jq * 4);
    float4 rr[4];
#pragma unroll
    for (int mm = 0; mm < 4; ++mm) {
        rr[mm].x = fmaxf(acc[mm].x + bv.x, 0.f);
        rr[mm].y = fmaxf(acc[mm].y + bv.y, 0.f);
        rr[mm].z = fmaxf(acc[mm].z + bv.z, 0.f);
        rr[mm].w = fmaxf(acc[mm].w + bv.w, 0.f);
    }

    // phase 2: [u|v] = relu(h1_tile) @ [W2l|W2r]
    __syncthreads();
#pragma unroll
    for (int mm = 0; mm < 4; ++mm)
        *(float4*)(smem + (mq * 4 + mm) * H1S + jq * 4) = rr[mm];
    __syncthreads();

    int jq2 = threadIdx.x & 31;         // 32 j-quads over combined [u(16)|v(16)]
    int mq2 = threadIdx.x >> 5;         // nodes mq2*4+mm
    float4 acc2[4] = {};
    const float* w2 = ((jq2 < 16) ? W2l + jq2 * 4 : W2r + (jq2 - 16) * 4);
#pragma unroll 2
    for (int k = 0; k < HID; k += 4) {
        float4 wv[4];
#pragma unroll
        for (int kk = 0; kk < 4; ++kk)
            wv[kk] = *(const float4*)(w2 + (k + kk) * OUTD);
#pragma unroll
        for (int mm = 0; mm < 4; ++mm) {
            float4 hv = *(const float4*)(smem + (mq2 * 4 + mm) * H1S + k);
            acc2[mm] = fma4(hv.x, wv[0], acc2[mm]);
            acc2[mm] = fma4(hv.y, wv[1], acc2[mm]);
            acc2[mm] = fma4(hv.z, wv[2], acc2[mm]);
            acc2[mm] = fma4(hv.w, wv[3], acc2[mm]);
        }
    }

#pragma unroll
    for (int mm = 0; mm < 4; ++mm) {
        int n = n0 + mq2 * 4 + mm;
        if (n < N) {
            if (jq2 < 16) {
                ushort4 p;
                p.x = f2bf(acc2[mm].x);
                p.y = f2bf(acc2[mm].y);
                p.z = f2bf(acc2[mm].z);
                p.w = f2bf(acc2[mm].w);
                *(ushort4*)(ub + (n << 6) + jq2 * 4) = p;
            } else {
                *(float4*)(vv + (n << 6) + (jq2 - 16) * 4) = acc2[mm];
            }
        }
    }
}

// ---- finalize: h2 = aggu + v + b2, then run-length segment-max ----------
__global__ __launch_bounds__(256) void finalize_kernel(
        const float* __restrict__ aggu, const float* __restrict__ vv,
        const float* __restrict__ b2, const int* __restrict__ batch,
        float* __restrict__ out, int N) {
    int j  = threadIdx.x & 63;
    int nq = threadIdx.x >> 6;
    int n0 = blockIdx.x * SEG_NODES;
    float bj = b2[j];
    int curg = -1;
    float curm = -__builtin_inff();
    for (int m = nq; m < SEG_NODES; m += 4) {
        int n = n0 + m;
        if (n >= N) break;
        int g = batch[n];
        float v = aggu[(n << 6) + j] + vv[(n << 6) + j] + bj;
        if (g != curg) {
            if (curg >= 0) atomicMaxF(&out[(curg << 6) + j], curm);
            curg = g;
            curm = v;
        } else {
            curm = fmaxf(curm, v);
        }
    }
    if (curg >= 0) atomicMaxF(&out[(curg << 6) + j], curm);
}

static inline size_t align256(size_t v) { return (v + 255) & ~(size_t)255; }

extern "C" void kernel_launch(void* const* d_in, const int* in_sizes, int n_in,
                              void* d_out, int out_size, void* d_ws, size_t ws_size,
                              hipStream_t stream) {
    const float* x     = (const float*)d_in[0];
    const float* votes = (const float*)d_in[1];
    const int*   eidx  = (const int*)d_in[2];
    const int*   batch = (const int*)d_in[3];
    const float* W1l   = (const float*)d_in[4];
    const float* b1    = (const float*)d_in[5];
    const float* W1r   = (const float*)d_in[6];
    const float* W2l   = (const float*)d_in[7];
    const float* b2    = (const float*)d_in[8];
    const float* W2r   = (const float*)d_in[9];
    float* out = (float*)d_out;

    const int N = in_sizes[1];
    const int E = in_sizes[2] / 2;
    const int* src = eidx;
    const int* dst = eidx + E;
    const int nb = (N + CHUNK - 1) / CHUNK;

    char* ws = (char*)d_ws;
    size_t off = 0;
    int* deg_i      = (int*)(ws + off); off = align256(off + (size_t)N * 4);
    int* row_start  = (int*)(ws + off); off = align256(off + (size_t)(N + 1) * 4);
    int* cursor     = (int*)(ws + off); off = align256(off + (size_t)N * 4);
    int* bsum       = (int*)(ws + off); off = align256(off + (size_t)nb * 4);
    int* bsum_ex    = (int*)(ws + off); off = align256(off + (size_t)nb * 4);
    int* sorted_src = (int*)(ws + off); off = align256(off + (size_t)E * 4);
    ushort_t* xb    = (ushort_t*)(ws + off); off = align256(off + (size_t)N * IN_F * 2);
    ushort_t* agg1b = (ushort_t*)(ws + off); off = align256(off + (size_t)N * IN_F * 2);
    ushort_t* ub    = (ushort_t*)(ws + off); off = align256(off + (size_t)N * OUTD * 2);
    float* vv       = (float*)(ws + off); off = align256(off + (size_t)N * OUTD * 4);
    float* aggu     = (float*)(ws + off); off = align256(off + (size_t)N * OUTD * 4);

    hipMemsetAsync(deg_i, 0, (size_t)N * 4, stream);
    init_out_kernel<<<(out_size + 255) / 256, 256, 0, stream>>>(out, out_size);

    // CSR
    hist_kernel<<<(E + 255) / 256, 256, 0, stream>>>(dst, deg_i, E);
    chunk_sum_kernel<<<nb, 256, 0, stream>>>(deg_i, bsum, N);
    scan_bsum_kernel<<<1, 64, 0, stream>>>(bsum, bsum_ex, nb);
    write_rows_kernel<<<nb, 256, 0, stream>>>(deg_i, bsum_ex, row_start, cursor, N, E);
    place_kernel<<<(E + 255) / 256, 256, 0, stream>>>(src, dst, cursor, sorted_src, E);

    // h0 -> bf16
    convert_kernel<<<(N * IN_F + 255) / 256, 256, 0, stream>>>(x, votes, xb, N);

    // layer 1 aggregate + both dense layers' matmuls (h1 stays in LDS)
    gather1_kernel<<<(N + 3) / 4, 256, 0, stream>>>(xb, row_start, sorted_src, agg1b, N);
    gemm1_kernel<<<(N + T1_M - 1) / T1_M, 256, 0, stream>>>(x, votes, agg1b, W1l, b1, W1r,
                                                            W2l, W2r, ub, vv, N);
    // layer 2 aggregate (64 dims, bf16)
    gatheru_kernel<<<(N + 3) / 4, 256, 0, stream>>>(ub, row_start, sorted_src, aggu, N);

    // h2 = aggu + v + b2, fused with segment-max
    finalize_kernel<<<(N + SEG_NODES - 1) / SEG_NODES, 256, 0, stream>>>(
        aggu, vv, b2, batch, out, N);
}